// Round 1
// baseline (1111.636 us; speedup 1.0000x reference)
//
#include <hip/hip_runtime.h>

// URGCN layer, MI355X.
// Key algebraic transform: (sum_e (x_src + r_rel)) @ Wn  ==  sum_e ((x_src + r_rel) @ Wn)
// so the 600k-row GEMM collapses to a scatter-add + one 50k-row GEMM.

constexpr int NNODES = 50000;
constexpr int NEDGES = 600000;
constexpr int DIM    = 128;

constexpr int NT = 32;   // nodes per block in finalize
constexpr int KS = 32;   // k-slice staged in LDS
constexpr int ATP = 36;  // padded inner dim for transposed staging (36%4==0 for float4 align)

// ---------------------------------------------------------------------------
// Kernel 1: edge scatter.  32 lanes per edge, float4 per lane (512B row).
// acc (= d_out) accumulates  nodes[src] + rel_embed[rel]  at row dst.
// cnt[dst] += 1 once per edge.
// ---------------------------------------------------------------------------
__global__ __launch_bounds__(256) void edge_scatter(
    const float* __restrict__ nodes, const float* __restrict__ rels,
    const int* __restrict__ edges, float* __restrict__ acc,
    float* __restrict__ cnt)
{
    int tid = blockIdx.x * 256 + threadIdx.x;
    int e = tid >> 5;
    if (e >= NEDGES) return;
    int c = tid & 31;

    int src = edges[e * 3 + 0];
    int rel = edges[e * 3 + 1];
    int dst = edges[e * 3 + 2];

    float4 hv = *(const float4*)(nodes + (size_t)src * DIM + c * 4);
    float4 rv = *(const float4*)(rels  + (size_t)rel * DIM + c * 4);

    float* p = acc + (size_t)dst * DIM + c * 4;
    atomicAdd(p + 0, hv.x + rv.x);
    atomicAdd(p + 1, hv.y + rv.y);
    atomicAdd(p + 2, hv.z + rv.z);
    atomicAdd(p + 3, hv.w + rv.w);
    if (c == 0) atomicAdd(cnt + dst, 1.0f);
}

// ---------------------------------------------------------------------------
// Kernel 2: finalize.  Per 32-node tile:
//   out[n] = h[n] + has_in ? (acc[n]/cnt[n]) @ Wn + h[n] @ Wself
//                          : h[n] @ Wself_evolve
// Dual vector-GEMM, 4x4 register micro-tile per thread, W in LDS k-slices.
// Thread layout: jg = t&31 -> cols j0=4*jg ; ig = t>>5 -> nodes i0=4*ig.
// ---------------------------------------------------------------------------
__global__ __launch_bounds__(256) void finalize(
    const float* __restrict__ nodes,
    const float* __restrict__ wn,    // w_neighbor  [k][j]
    const float* __restrict__ wsf,   // w_self      [k][j]
    const float* __restrict__ wse,   // w_self_evolve
    const float* __restrict__ cnt,
    float* __restrict__ acc_out)     // in: msg_sum ; out: final embedding
{
    __shared__ float WnL[KS][DIM];
    __shared__ float WsL[KS][DIM];
    __shared__ float aT[KS][ATP];
    __shared__ float hT[KS][ATP];
    __shared__ float cntL[NT];

    const int t  = threadIdx.x;
    const int n0 = blockIdx.x * NT;
    const int j0 = (t & 31) * 4;
    const int i0 = (t >> 5) * 4;

    if (t < NT) {
        int n = n0 + t;
        cntL[t] = (n < NNODES) ? cnt[n] : 1.0f;
    }

    float accN[4][4] = {};
    float accS[4][4] = {};

    for (int ks = 0; ks < DIM; ks += KS) {
        __syncthreads();
        // stage W slices: KS*DIM floats = 1024 float4 -> 4 per thread
        #pragma unroll
        for (int r = 0; r < 4; ++r) {
            int idx = t + r * 256;
            int kk  = idx >> 5;
            int jj4 = (idx & 31) * 4;
            *(float4*)&WnL[kk][jj4] = *(const float4*)(wn  + (size_t)(ks + kk) * DIM + jj4);
            *(float4*)&WsL[kk][jj4] = *(const float4*)(wsf + (size_t)(ks + kk) * DIM + jj4);
        }
        // stage transposed acc & h slices: 32 nodes x 32 k
        {
            int ii  = t >> 3;          // node 0..31
            int kk4 = (t & 7) * 4;     // k within slice
            int n   = n0 + ii;
            int ncl = n < NNODES ? n : NNODES - 1;
            float4 av = *(const float4*)(acc_out + (size_t)ncl * DIM + ks + kk4);
            float4 hv = *(const float4*)(nodes   + (size_t)ncl * DIM + ks + kk4);
            aT[kk4 + 0][ii] = av.x; aT[kk4 + 1][ii] = av.y;
            aT[kk4 + 2][ii] = av.z; aT[kk4 + 3][ii] = av.w;
            hT[kk4 + 0][ii] = hv.x; hT[kk4 + 1][ii] = hv.y;
            hT[kk4 + 2][ii] = hv.z; hT[kk4 + 3][ii] = hv.w;
        }
        __syncthreads();

        #pragma unroll 8
        for (int kk = 0; kk < KS; ++kk) {
            float4 wnv = *(const float4*)&WnL[kk][j0];
            float4 wsv = *(const float4*)&WsL[kk][j0];
            float4 av  = *(const float4*)&aT[kk][i0];
            float4 hv  = *(const float4*)&hT[kk][i0];
            float an[4] = {av.x, av.y, av.z, av.w};
            float hn[4] = {hv.x, hv.y, hv.z, hv.w};
            float wl[4] = {wnv.x, wnv.y, wnv.z, wnv.w};
            float sl[4] = {wsv.x, wsv.y, wsv.z, wsv.w};
            #pragma unroll
            for (int a = 0; a < 4; ++a)
                #pragma unroll
                for (int b = 0; b < 4; ++b) {
                    accN[a][b] += an[a] * wl[b];
                    accS[a][b] += hn[a] * sl[b];
                }
        }
    }
    __syncthreads();   // all global reads of acc rows done before overwrite

    #pragma unroll
    for (int a = 0; a < 4; ++a) {
        int n = n0 + i0 + a;
        if (n >= NNODES) continue;
        float c = cntL[i0 + a];
        float4 hv = *(const float4*)(nodes + (size_t)n * DIM + j0);
        float4 o;
        if (c > 0.0f) {
            float inv = 1.0f / c;
            o.x = hv.x + accN[a][0] * inv + accS[a][0];
            o.y = hv.y + accN[a][1] * inv + accS[a][1];
            o.z = hv.z + accN[a][2] * inv + accS[a][2];
            o.w = hv.w + accN[a][3] * inv + accS[a][3];
        } else {
            // rare path (~e^-12 per node): self-evolve matmul from global
            float s0 = 0, s1 = 0, s2 = 0, s3 = 0;
            for (int k = 0; k < DIM; ++k) {
                float hk = nodes[(size_t)n * DIM + k];
                const float* wr = wse + (size_t)k * DIM + j0;
                s0 += hk * wr[0]; s1 += hk * wr[1];
                s2 += hk * wr[2]; s3 += hk * wr[3];
            }
            o.x = hv.x + s0; o.y = hv.y + s1;
            o.z = hv.z + s2; o.w = hv.w + s3;
        }
        *(float4*)(acc_out + (size_t)n * DIM + j0) = o;
    }
}

// ---------------------------------------------------------------------------
extern "C" void kernel_launch(void* const* d_in, const int* in_sizes, int n_in,
                              void* d_out, int out_size, void* d_ws, size_t ws_size,
                              hipStream_t stream)
{
    const float* nodes = (const float*)d_in[0];
    const float* rels  = (const float*)d_in[1];
    const int*   edges = (const int*)d_in[2];
    const float* wn    = (const float*)d_in[3];
    const float* wsf   = (const float*)d_in[4];
    const float* wse   = (const float*)d_in[5];
    float* out = (float*)d_out;
    float* cnt = (float*)d_ws;

    hipMemsetAsync(out, 0, (size_t)NNODES * DIM * sizeof(float), stream);
    hipMemsetAsync(cnt, 0, (size_t)NNODES * sizeof(float), stream);

    int eb = (NEDGES * 32) / 256;              // 75000 blocks
    edge_scatter<<<eb, 256, 0, stream>>>(nodes, rels, edges, out, cnt);

    int nb = (NNODES + NT - 1) / NT;           // 1563 blocks
    finalize<<<nb, 256, 0, stream>>>(nodes, wn, wsf, wse, cnt, out);
}

// Round 2
// 296.630 us; speedup vs baseline: 3.7476x; 3.7476x over previous
//
#include <hip/hip_runtime.h>

// URGCN layer, MI355X.
// Round 2: replace the 76.8M memory-side f32 atomics (1.25 GB HBM write-through,
// 1040us) with an on-the-fly counting sort (CSR by dst) + atomic-free gather.
//
//   (sum_e (x_src + r_rel)) @ Wn == sum_e ((x_src + r_rel)) @ Wn   (linearity)
//
// Pipeline: hist (int atomics) -> scan (1 block) -> fill (bucket scatter)
//           -> gather (owner-computes, register accumulate) -> finalize (GEMMs)

constexpr int NNODES = 50000;
constexpr int NEDGES = 600000;
constexpr int DIM    = 128;

constexpr int NT = 32;   // nodes per block in finalize
constexpr int KS = 32;   // k-slice staged in LDS
constexpr int ATP = 36;  // padded inner dim for transposed staging

// ---------------- workspace layout (bytes) ----------------
// cnt    : int[50000]   @ 0
// off    : int[50001]   @ OFF_CNT_B
// cursor : int[50000]   @ OFF_CUR_B
// buckets: int2[600000] @ OFF_BKT_B        total ~5.42 MB
constexpr size_t OFF_CNT_B = 0;
constexpr size_t OFF_OFF_B = 204800;
constexpr size_t OFF_CUR_B = 409600;
constexpr size_t OFF_BKT_B = 614400;

// ---------------------------------------------------------------------------
__global__ __launch_bounds__(256) void hist(const int* __restrict__ edges,
                                            int* __restrict__ cnt)
{
    int e = blockIdx.x * 256 + threadIdx.x;
    if (e >= NEDGES) return;
    atomicAdd(cnt + edges[e * 3 + 2], 1);
}

// Single-block exclusive scan of cnt[NNODES] -> off[], cursor[]; off[NNODES]=E.
__global__ __launch_bounds__(1024) void scan_offsets(const int* __restrict__ cnt,
                                                     int* __restrict__ off,
                                                     int* __restrict__ cursor)
{
    __shared__ int part[1024];
    const int t  = threadIdx.x;
    const int CH = (NNODES + 1023) / 1024;    // 49
    const int base = t * CH;

    int s = 0;
    for (int i = 0; i < CH; ++i) {
        int idx = base + i;
        if (idx < NNODES) s += cnt[idx];
    }
    part[t] = s;
    __syncthreads();
    // Hillis-Steele inclusive scan
    for (int d = 1; d < 1024; d <<= 1) {
        int v = (t >= d) ? part[t - d] : 0;
        __syncthreads();
        part[t] += v;
        __syncthreads();
    }
    int run = (t == 0) ? 0 : part[t - 1];
    for (int i = 0; i < CH; ++i) {
        int idx = base + i;
        if (idx < NNODES) {
            off[idx] = run;
            cursor[idx] = run;
            run += cnt[idx];
        }
    }
    if (t == 1023) off[NNODES] = run;
}

__global__ __launch_bounds__(256) void fill(const int* __restrict__ edges,
                                            int* __restrict__ cursor,
                                            int2* __restrict__ buckets)
{
    int e = blockIdx.x * 256 + threadIdx.x;
    if (e >= NEDGES) return;
    int src = edges[e * 3 + 0];
    int rel = edges[e * 3 + 1];
    int dst = edges[e * 3 + 2];
    int pos = atomicAdd(cursor + dst, 1);
    buckets[pos] = make_int2(src, rel);
}

// ---------------------------------------------------------------------------
// gather: 32 lanes (float4) per node; walk the node's bucket, accumulate
// nodes[src]+rels[rel] in registers, one coalesced 512B row write. No atomics.
// ---------------------------------------------------------------------------
__global__ __launch_bounds__(256) void gather(const float* __restrict__ nodes,
                                              const float* __restrict__ rels,
                                              const int* __restrict__ off,
                                              const int2* __restrict__ buckets,
                                              float* __restrict__ out)
{
    int tid = blockIdx.x * 256 + threadIdx.x;
    int n = tid >> 5;
    if (n >= NNODES) return;
    int lane = tid & 31;

    int beg = off[n];
    int end = off[n + 1];

    float4 acc = make_float4(0.f, 0.f, 0.f, 0.f);
    int i = beg;
    // 2-deep manual pipeline for independent load chains
    for (; i + 1 < end; i += 2) {
        int2 e0 = buckets[i];
        int2 e1 = buckets[i + 1];
        float4 h0 = *(const float4*)(nodes + (size_t)e0.x * DIM + lane * 4);
        float4 r0 = *(const float4*)(rels  + (size_t)e0.y * DIM + lane * 4);
        float4 h1 = *(const float4*)(nodes + (size_t)e1.x * DIM + lane * 4);
        float4 r1 = *(const float4*)(rels  + (size_t)e1.y * DIM + lane * 4);
        acc.x += h0.x + r0.x; acc.y += h0.y + r0.y;
        acc.z += h0.z + r0.z; acc.w += h0.w + r0.w;
        acc.x += h1.x + r1.x; acc.y += h1.y + r1.y;
        acc.z += h1.z + r1.z; acc.w += h1.w + r1.w;
    }
    if (i < end) {
        int2 e0 = buckets[i];
        float4 h0 = *(const float4*)(nodes + (size_t)e0.x * DIM + lane * 4);
        float4 r0 = *(const float4*)(rels  + (size_t)e0.y * DIM + lane * 4);
        acc.x += h0.x + r0.x; acc.y += h0.y + r0.y;
        acc.z += h0.z + r0.z; acc.w += h0.w + r0.w;
    }
    *(float4*)(out + (size_t)n * DIM + lane * 4) = acc;
}

// ---------------------------------------------------------------------------
// finalize: out[n] = h[n] + (deg>0 ? msg_sum[n]/deg @ Wn + h[n]@Wself
//                                  : h[n]@Wself_evolve)
// Dual vector-GEMM, 4x4 register micro-tile per thread, W in LDS k-slices.
// ---------------------------------------------------------------------------
__global__ __launch_bounds__(256) void finalize(
    const float* __restrict__ nodes,
    const float* __restrict__ wn,
    const float* __restrict__ wsf,
    const float* __restrict__ wse,
    const int* __restrict__ off,
    float* __restrict__ acc_out)     // in: msg_sum ; out: final embedding
{
    __shared__ float WnL[KS][DIM];
    __shared__ float WsL[KS][DIM];
    __shared__ float aT[KS][ATP];
    __shared__ float hT[KS][ATP];
    __shared__ float cntL[NT];

    const int t  = threadIdx.x;
    const int n0 = blockIdx.x * NT;
    const int j0 = (t & 31) * 4;
    const int i0 = (t >> 5) * 4;

    if (t < NT) {
        int n = n0 + t;
        cntL[t] = (n < NNODES) ? (float)(off[n + 1] - off[n]) : 1.0f;
    }

    float accN[4][4] = {};
    float accS[4][4] = {};

    for (int ks = 0; ks < DIM; ks += KS) {
        __syncthreads();
        #pragma unroll
        for (int r = 0; r < 4; ++r) {
            int idx = t + r * 256;
            int kk  = idx >> 5;
            int jj4 = (idx & 31) * 4;
            *(float4*)&WnL[kk][jj4] = *(const float4*)(wn  + (size_t)(ks + kk) * DIM + jj4);
            *(float4*)&WsL[kk][jj4] = *(const float4*)(wsf + (size_t)(ks + kk) * DIM + jj4);
        }
        {
            int ii  = t >> 3;
            int kk4 = (t & 7) * 4;
            int n   = n0 + ii;
            int ncl = n < NNODES ? n : NNODES - 1;
            float4 av = *(const float4*)(acc_out + (size_t)ncl * DIM + ks + kk4);
            float4 hv = *(const float4*)(nodes   + (size_t)ncl * DIM + ks + kk4);
            aT[kk4 + 0][ii] = av.x; aT[kk4 + 1][ii] = av.y;
            aT[kk4 + 2][ii] = av.z; aT[kk4 + 3][ii] = av.w;
            hT[kk4 + 0][ii] = hv.x; hT[kk4 + 1][ii] = hv.y;
            hT[kk4 + 2][ii] = hv.z; hT[kk4 + 3][ii] = hv.w;
        }
        __syncthreads();

        #pragma unroll 8
        for (int kk = 0; kk < KS; ++kk) {
            float4 wnv = *(const float4*)&WnL[kk][j0];
            float4 wsv = *(const float4*)&WsL[kk][j0];
            float4 av  = *(const float4*)&aT[kk][i0];
            float4 hv  = *(const float4*)&hT[kk][i0];
            float an[4] = {av.x, av.y, av.z, av.w};
            float hn[4] = {hv.x, hv.y, hv.z, hv.w};
            float wl[4] = {wnv.x, wnv.y, wnv.z, wnv.w};
            float sl[4] = {wsv.x, wsv.y, wsv.z, wsv.w};
            #pragma unroll
            for (int a = 0; a < 4; ++a)
                #pragma unroll
                for (int b = 0; b < 4; ++b) {
                    accN[a][b] += an[a] * wl[b];
                    accS[a][b] += hn[a] * sl[b];
                }
        }
    }
    __syncthreads();   // all LDS staging reads of acc rows done before overwrite

    #pragma unroll
    for (int a = 0; a < 4; ++a) {
        int n = n0 + i0 + a;
        if (n >= NNODES) continue;
        float c = cntL[i0 + a];
        float4 hv = *(const float4*)(nodes + (size_t)n * DIM + j0);
        float4 o;
        if (c > 0.0f) {
            float inv = 1.0f / c;
            o.x = hv.x + accN[a][0] * inv + accS[a][0];
            o.y = hv.y + accN[a][1] * inv + accS[a][1];
            o.z = hv.z + accN[a][2] * inv + accS[a][2];
            o.w = hv.w + accN[a][3] * inv + accS[a][3];
        } else {
            // rare path (~6e-6 per node): self-evolve matmul from global
            float s0 = 0, s1 = 0, s2 = 0, s3 = 0;
            for (int k = 0; k < DIM; ++k) {
                float hk = nodes[(size_t)n * DIM + k];
                const float* wr = wse + (size_t)k * DIM + j0;
                s0 += hk * wr[0]; s1 += hk * wr[1];
                s2 += hk * wr[2]; s3 += hk * wr[3];
            }
            o.x = hv.x + s0; o.y = hv.y + s1;
            o.z = hv.z + s2; o.w = hv.w + s3;
        }
        *(float4*)(acc_out + (size_t)n * DIM + j0) = o;
    }
}

// ---------------------------------------------------------------------------
extern "C" void kernel_launch(void* const* d_in, const int* in_sizes, int n_in,
                              void* d_out, int out_size, void* d_ws, size_t ws_size,
                              hipStream_t stream)
{
    const float* nodes = (const float*)d_in[0];
    const float* rels  = (const float*)d_in[1];
    const int*   edges = (const int*)d_in[2];
    const float* wn    = (const float*)d_in[3];
    const float* wsf   = (const float*)d_in[4];
    const float* wse   = (const float*)d_in[5];
    float* out = (float*)d_out;

    char* ws = (char*)d_ws;
    int*  cnt     = (int*)(ws + OFF_CNT_B);
    int*  off     = (int*)(ws + OFF_OFF_B);
    int*  cursor  = (int*)(ws + OFF_CUR_B);
    int2* buckets = (int2*)(ws + OFF_BKT_B);

    hipMemsetAsync(cnt, 0, (size_t)NNODES * sizeof(int), stream);

    int eb = (NEDGES + 255) / 256;             // 2344 blocks
    hist<<<eb, 256, 0, stream>>>(edges, cnt);
    scan_offsets<<<1, 1024, 0, stream>>>(cnt, off, cursor);
    fill<<<eb, 256, 0, stream>>>(edges, cursor, buckets);

    int gb = (NNODES * 32 + 255) / 256;        // 6250 blocks
    gather<<<gb, 256, 0, stream>>>(nodes, rels, off, buckets, out);

    int nb = (NNODES + NT - 1) / NT;           // 1563 blocks
    finalize<<<nb, 256, 0, stream>>>(nodes, wn, wsf, wse, off, out);
}

// Round 3
// 177.291 us; speedup vs baseline: 6.2701x; 1.6731x over previous
//
#include <hip/hip_runtime.h>

// URGCN layer, MI355X.
// Round 3: parallelize the exclusive scan (was a 125us single-block kernel =
// 42% of runtime), pack buckets to 4B, full-wave-per-node gather.
//
// Pipeline: hist -> scan{partial,bsum,final} -> fill -> gather -> finalize

constexpr int NNODES = 50000;
constexpr int NEDGES = 600000;
constexpr int DIM    = 128;

constexpr int NT = 32;   // nodes per block in finalize
constexpr int KS = 32;   // k-slice staged in LDS
constexpr int ATP = 36;  // padded inner dim for transposed staging

constexpr int SCB = 256;                       // elements per scan block
constexpr int NSB = (NNODES + SCB - 1) / SCB;  // 196 scan blocks

// ---------------- workspace layout (bytes) ----------------
constexpr size_t OFF_CNT_B = 0;        // int[50000]
constexpr size_t OFF_OFF_B = 204800;   // int[50001]
constexpr size_t OFF_CUR_B = 409600;   // int[50000]
constexpr size_t OFF_BSM_B = 614400;   // int[NSB]
constexpr size_t OFF_BBS_B = 618496;   // int[256]
constexpr size_t OFF_BKT_B = 622592;   // uint[600000]  (packed src|rel<<16)

// ---------------------------------------------------------------------------
__global__ __launch_bounds__(256) void hist(const int* __restrict__ edges,
                                            int* __restrict__ cnt)
{
    int e = blockIdx.x * 256 + threadIdx.x;
    if (e >= NEDGES) return;
    atomicAdd(cnt + edges[e * 3 + 2], 1);
}

// --- scan phase 1: per-block sums of cnt ---
__global__ __launch_bounds__(SCB) void scan_partial(const int* __restrict__ cnt,
                                                    int* __restrict__ bsum)
{
    int gid = blockIdx.x * SCB + threadIdx.x;
    int v = (gid < NNODES) ? cnt[gid] : 0;
    #pragma unroll
    for (int d = 32; d > 0; d >>= 1) v += __shfl_down(v, d, 64);
    __shared__ int ws[SCB / 64];
    if ((threadIdx.x & 63) == 0) ws[threadIdx.x >> 6] = v;
    __syncthreads();
    if (threadIdx.x == 0) {
        int s = 0;
        #pragma unroll
        for (int w = 0; w < SCB / 64; ++w) s += ws[w];
        bsum[blockIdx.x] = s;
    }
}

// --- scan phase 2: 1-block exclusive scan of the NSB block sums ---
__global__ __launch_bounds__(256) void scan_bsum(const int* __restrict__ bsum,
                                                 int* __restrict__ bbase,
                                                 int* __restrict__ off)
{
    __shared__ int sh[256];
    int t = threadIdx.x;
    int v = (t < NSB) ? bsum[t] : 0;
    sh[t] = v;
    __syncthreads();
    #pragma unroll
    for (int d = 1; d < 256; d <<= 1) {
        int u = (t >= d) ? sh[t - d] : 0;
        __syncthreads();
        sh[t] += u;
        __syncthreads();
    }
    bbase[t] = (t == 0) ? 0 : sh[t - 1];
    if (t == 255) off[NNODES] = sh[255];
}

// --- scan phase 3: block-local exclusive scan + block base ---
__global__ __launch_bounds__(SCB) void scan_final(const int* __restrict__ cnt,
                                                  const int* __restrict__ bbase,
                                                  int* __restrict__ off,
                                                  int* __restrict__ cursor)
{
    __shared__ int sh[SCB];
    int t = threadIdx.x;
    int gid = blockIdx.x * SCB + t;
    int v = (gid < NNODES) ? cnt[gid] : 0;
    sh[t] = v;
    __syncthreads();
    #pragma unroll
    for (int d = 1; d < SCB; d <<= 1) {
        int u = (t >= d) ? sh[t - d] : 0;
        __syncthreads();
        sh[t] += u;
        __syncthreads();
    }
    if (gid < NNODES) {
        int excl = bbase[blockIdx.x] + ((t == 0) ? 0 : sh[t - 1]);
        off[gid] = excl;
        cursor[gid] = excl;
    }
}

// ---------------------------------------------------------------------------
__global__ __launch_bounds__(256) void fill(const int* __restrict__ edges,
                                            int* __restrict__ cursor,
                                            unsigned* __restrict__ buckets)
{
    int e = blockIdx.x * 256 + threadIdx.x;
    if (e >= NEDGES) return;
    int src = edges[e * 3 + 0];
    int rel = edges[e * 3 + 1];
    int dst = edges[e * 3 + 2];
    int pos = atomicAdd(cursor + dst, 1);
    buckets[pos] = (unsigned)src | ((unsigned)rel << 16);
}

// ---------------------------------------------------------------------------
// gather: full wave (64 lanes) per node. Half h walks bucket entries
// beg+h, beg+h+2, ...; lanes (l&31) hold float4 columns. Cross-half
// __shfl_xor reduce, lower half writes the 512B row. No atomics.
// ---------------------------------------------------------------------------
__global__ __launch_bounds__(256) void gather(const float* __restrict__ nodes,
                                              const float* __restrict__ rels,
                                              const int* __restrict__ off,
                                              const unsigned* __restrict__ buckets,
                                              float* __restrict__ out)
{
    int tid = blockIdx.x * 256 + threadIdx.x;
    int n = tid >> 6;
    if (n >= NNODES) return;
    int lane = threadIdx.x & 63;
    int half = lane >> 5;
    int c4 = (lane & 31) * 4;

    int beg = off[n];
    int end = off[n + 1];

    float4 acc = make_float4(0.f, 0.f, 0.f, 0.f);
    int i = beg + half;
    // depth-2 unroll: 4 edges in flight per wave
    for (; i + 2 < end; i += 4) {
        unsigned b0 = buckets[i];
        unsigned b1 = buckets[i + 2];
        const float* h0p = nodes + (size_t)(b0 & 0xFFFFu) * DIM + c4;
        const float* r0p = rels  + (size_t)(b0 >> 16)      * DIM + c4;
        const float* h1p = nodes + (size_t)(b1 & 0xFFFFu) * DIM + c4;
        const float* r1p = rels  + (size_t)(b1 >> 16)      * DIM + c4;
        float4 h0 = *(const float4*)h0p;
        float4 r0 = *(const float4*)r0p;
        float4 h1 = *(const float4*)h1p;
        float4 r1 = *(const float4*)r1p;
        acc.x += h0.x + r0.x; acc.y += h0.y + r0.y;
        acc.z += h0.z + r0.z; acc.w += h0.w + r0.w;
        acc.x += h1.x + r1.x; acc.y += h1.y + r1.y;
        acc.z += h1.z + r1.z; acc.w += h1.w + r1.w;
    }
    if (i < end) {
        unsigned b0 = buckets[i];
        float4 h0 = *(const float4*)(nodes + (size_t)(b0 & 0xFFFFu) * DIM + c4);
        float4 r0 = *(const float4*)(rels  + (size_t)(b0 >> 16)      * DIM + c4);
        acc.x += h0.x + r0.x; acc.y += h0.y + r0.y;
        acc.z += h0.z + r0.z; acc.w += h0.w + r0.w;
    }

    acc.x += __shfl_xor(acc.x, 32, 64);
    acc.y += __shfl_xor(acc.y, 32, 64);
    acc.z += __shfl_xor(acc.z, 32, 64);
    acc.w += __shfl_xor(acc.w, 32, 64);

    if (half == 0)
        *(float4*)(out + (size_t)n * DIM + c4) = acc;
}

// ---------------------------------------------------------------------------
// finalize: out[n] = h[n] + (deg>0 ? msg_sum[n]/deg @ Wn + h[n]@Wself
//                                  : h[n]@Wself_evolve)
// ---------------------------------------------------------------------------
__global__ __launch_bounds__(256) void finalize(
    const float* __restrict__ nodes,
    const float* __restrict__ wn,
    const float* __restrict__ wsf,
    const float* __restrict__ wse,
    const int* __restrict__ off,
    float* __restrict__ acc_out)
{
    __shared__ float WnL[KS][DIM];
    __shared__ float WsL[KS][DIM];
    __shared__ float aT[KS][ATP];
    __shared__ float hT[KS][ATP];
    __shared__ float cntL[NT];

    const int t  = threadIdx.x;
    const int n0 = blockIdx.x * NT;
    const int j0 = (t & 31) * 4;
    const int i0 = (t >> 5) * 4;

    if (t < NT) {
        int n = n0 + t;
        cntL[t] = (n < NNODES) ? (float)(off[n + 1] - off[n]) : 1.0f;
    }

    float accN[4][4] = {};
    float accS[4][4] = {};

    for (int ks = 0; ks < DIM; ks += KS) {
        __syncthreads();
        #pragma unroll
        for (int r = 0; r < 4; ++r) {
            int idx = t + r * 256;
            int kk  = idx >> 5;
            int jj4 = (idx & 31) * 4;
            *(float4*)&WnL[kk][jj4] = *(const float4*)(wn  + (size_t)(ks + kk) * DIM + jj4);
            *(float4*)&WsL[kk][jj4] = *(const float4*)(wsf + (size_t)(ks + kk) * DIM + jj4);
        }
        {
            int ii  = t >> 3;
            int kk4 = (t & 7) * 4;
            int n   = n0 + ii;
            int ncl = n < NNODES ? n : NNODES - 1;
            float4 av = *(const float4*)(acc_out + (size_t)ncl * DIM + ks + kk4);
            float4 hv = *(const float4*)(nodes   + (size_t)ncl * DIM + ks + kk4);
            aT[kk4 + 0][ii] = av.x; aT[kk4 + 1][ii] = av.y;
            aT[kk4 + 2][ii] = av.z; aT[kk4 + 3][ii] = av.w;
            hT[kk4 + 0][ii] = hv.x; hT[kk4 + 1][ii] = hv.y;
            hT[kk4 + 2][ii] = hv.z; hT[kk4 + 3][ii] = hv.w;
        }
        __syncthreads();

        #pragma unroll 8
        for (int kk = 0; kk < KS; ++kk) {
            float4 wnv = *(const float4*)&WnL[kk][j0];
            float4 wsv = *(const float4*)&WsL[kk][j0];
            float4 av  = *(const float4*)&aT[kk][i0];
            float4 hv  = *(const float4*)&hT[kk][i0];
            float an[4] = {av.x, av.y, av.z, av.w};
            float hn[4] = {hv.x, hv.y, hv.z, hv.w};
            float wl[4] = {wnv.x, wnv.y, wnv.z, wnv.w};
            float sl[4] = {wsv.x, wsv.y, wsv.z, wsv.w};
            #pragma unroll
            for (int a = 0; a < 4; ++a)
                #pragma unroll
                for (int b = 0; b < 4; ++b) {
                    accN[a][b] += an[a] * wl[b];
                    accS[a][b] += hn[a] * sl[b];
                }
        }
    }
    __syncthreads();

    #pragma unroll
    for (int a = 0; a < 4; ++a) {
        int n = n0 + i0 + a;
        if (n >= NNODES) continue;
        float c = cntL[i0 + a];
        float4 hv = *(const float4*)(nodes + (size_t)n * DIM + j0);
        float4 o;
        if (c > 0.0f) {
            float inv = 1.0f / c;
            o.x = hv.x + accN[a][0] * inv + accS[a][0];
            o.y = hv.y + accN[a][1] * inv + accS[a][1];
            o.z = hv.z + accN[a][2] * inv + accS[a][2];
            o.w = hv.w + accN[a][3] * inv + accS[a][3];
        } else {
            float s0 = 0, s1 = 0, s2 = 0, s3 = 0;
            for (int k = 0; k < DIM; ++k) {
                float hk = nodes[(size_t)n * DIM + k];
                const float* wr = wse + (size_t)k * DIM + j0;
                s0 += hk * wr[0]; s1 += hk * wr[1];
                s2 += hk * wr[2]; s3 += hk * wr[3];
            }
            o.x = hv.x + s0; o.y = hv.y + s1;
            o.z = hv.z + s2; o.w = hv.w + s3;
        }
        *(float4*)(acc_out + (size_t)n * DIM + j0) = o;
    }
}

// ---------------------------------------------------------------------------
extern "C" void kernel_launch(void* const* d_in, const int* in_sizes, int n_in,
                              void* d_out, int out_size, void* d_ws, size_t ws_size,
                              hipStream_t stream)
{
    const float* nodes = (const float*)d_in[0];
    const float* rels  = (const float*)d_in[1];
    const int*   edges = (const int*)d_in[2];
    const float* wn    = (const float*)d_in[3];
    const float* wsf   = (const float*)d_in[4];
    const float* wse   = (const float*)d_in[5];
    float* out = (float*)d_out;

    char* ws = (char*)d_ws;
    int*      cnt     = (int*)(ws + OFF_CNT_B);
    int*      off     = (int*)(ws + OFF_OFF_B);
    int*      cursor  = (int*)(ws + OFF_CUR_B);
    int*      bsum    = (int*)(ws + OFF_BSM_B);
    int*      bbase   = (int*)(ws + OFF_BBS_B);
    unsigned* buckets = (unsigned*)(ws + OFF_BKT_B);

    hipMemsetAsync(cnt, 0, (size_t)NNODES * sizeof(int), stream);

    int eb = (NEDGES + 255) / 256;             // 2344 blocks
    hist<<<eb, 256, 0, stream>>>(edges, cnt);
    scan_partial<<<NSB, SCB, 0, stream>>>(cnt, bsum);
    scan_bsum<<<1, 256, 0, stream>>>(bsum, bbase, off);
    scan_final<<<NSB, SCB, 0, stream>>>(cnt, bbase, off, cursor);
    fill<<<eb, 256, 0, stream>>>(edges, cursor, buckets);

    int gb = (NNODES * 64 + 255) / 256;        // 12500 blocks
    gather<<<gb, 256, 0, stream>>>(nodes, rels, off, buckets, out);

    int nb = (NNODES + NT - 1) / NT;           // 1563 blocks
    finalize<<<nb, 256, 0, stream>>>(nodes, wn, wsf, wse, off, out);
}